// Round 4
// baseline (819.233 us; speedup 1.0000x reference)
//
#include <hip/hip_runtime.h>

#define EPSF 1e-6f

// Shapes: B=4, S=4096, H=8, D=128
// BS = 16384 rows; HD = 1024; ROW3 = 3072 (H*3*D); channels = B*H*D = 4096
// Scan chunking: 64 chunks of length 64 along S.
// Row-chunked middle section: CH rows per chunk, chosen from ws_size.

__device__ __forceinline__ float sigm(float x) { return 1.0f / (1.0f + __expf(-x)); }

// Block-wide (sum, sumsq) reduction; requires blockDim.x == 256.
__device__ __forceinline__ void block_reduce2(float& a, float& b) {
#pragma unroll
    for (int off = 32; off > 0; off >>= 1) {
        a += __shfl_down(a, off);
        b += __shfl_down(b, off);
    }
    __shared__ float sa[8], sb[8];
    int wid = threadIdx.x >> 6;
    int lane = threadIdx.x & 63;
    if (lane == 0) { sa[wid] = a; sb[wid] = b; }
    __syncthreads();
    a = sa[0] + sa[1] + sa[2] + sa[3];
    b = sb[0] + sb[1] + sb[2] + sb[3];
}

// ---- cumsum (exclusive prefix over S) ----
__global__ __launch_bounds__(256) void k_cumsum_a(const float* __restrict__ X, float* __restrict__ cS) {
    int t = blockIdx.x * 256 + threadIdx.x;          // 262144 total
    int d = t & 127, h = (t >> 7) & 7, k = (t >> 10) & 63, b = t >> 16;
    size_t base = (((size_t)(b * 4096 + k * 64)) * 8 + h) * 128 + d;
    float s = 0.f;
#pragma unroll 8
    for (int j = 0; j < 64; ++j) s += X[base + (size_t)j * 1024];
    cS[(size_t)((b * 8 + h) * 128 + d) * 64 + k] = s;
}

__global__ __launch_bounds__(256) void k_cumsum_b(const float* __restrict__ cS, float* __restrict__ cO) {
    int ch = blockIdx.x * 256 + threadIdx.x;          // 4096
    size_t base = (size_t)ch * 64;
    float off = 0.f;
    for (int k = 0; k < 64; ++k) { float v = cS[base + k]; cO[base + k] = off; off += v; }
}

__global__ __launch_bounds__(256) void k_cumsum_c(const float* __restrict__ X, const float* __restrict__ cO,
                                                  float* __restrict__ CSUM) {
    int t = blockIdx.x * 256 + threadIdx.x;
    int d = t & 127, h = (t >> 7) & 7, k = (t >> 10) & 63, b = t >> 16;
    int ch = (b * 8 + h) * 128 + d;
    float run = cO[(size_t)ch * 64 + k];
    size_t base = (((size_t)(b * 4096 + k * 64)) * 8 + h) * 128 + d;
    for (int j = 0; j < 64; ++j) {
        float x = X[base + (size_t)j * 1024];
        CSUM[base + (size_t)j * 1024] = run;
        run += x;
    }
}

// ---- LN over (h,d) per (b,s), in place on R0 ----
__global__ __launch_bounds__(256) void k_ln_csum(float* __restrict__ R0, const float* __restrict__ g,
                                                 const float* __restrict__ bb) {
    int bs = blockIdx.x, t = threadIdx.x;
    float4* row = (float4*)(R0 + (size_t)bs * 1024);
    float4 v = row[t];
    float s = v.x + v.y + v.z + v.w;
    float ss = v.x * v.x + v.y * v.y + v.z * v.z + v.w * v.w;
    block_reduce2(s, ss);
    float m = s * (1.f / 1024.f);
    float var = ss * (1.f / 1024.f) - m * m;
    float r = rsqrtf(fmaxf(var, 0.f) + EPSF);
    float4 gv = ((const float4*)g)[t];
    float4 bv = ((const float4*)bb)[t];
    v.x = (v.x - m) * r * gv.x + bv.x;
    v.y = (v.y - m) * r * gv.y + bv.y;
    v.z = (v.z - m) * r * gv.z + bv.z;
    v.w = (v.w - m) * r * gv.w + bv.w;
    row[t] = v;
}

// ---- tiled f32 GEMM per head over a row-chunk:
// OUT[((m-m0)*8+h)*Nw + o] = bias[h,o] + sum_k cat[m,h,k] * W[h,k,o],  m in [m0, m0+CH)
// cat col k<128 -> X[m,h,k] (absolute rows), else A2[m*1024 + h*128 + (k-128)] (absolute rows)
__global__ __launch_bounds__(256) void k_gemm(const float* __restrict__ X, const float* __restrict__ A2,
                                              const float* __restrict__ W, const float* __restrict__ bias,
                                              float* __restrict__ OUT, int Nw, int m0) {
    __shared__ float As[32][68];   // k-major, padded
    __shared__ float Bs[32][64];
    int h = blockIdx.z;
    int by = blockIdx.y;   // 64-row tile within chunk
    int bx = blockIdx.x;   // 64-col tile
    int t = threadIdx.x;
    int tx = t & 15, ty = t >> 4;
    float acc[4][4] = {};
    int kkA = t & 31, rA = t >> 5;  // A loader
    int oB = t & 63, kB = t >> 6;   // B loader
    for (int kt = 0; kt < 8; ++kt) {
        int k0 = kt * 32;
#pragma unroll
        for (int rr = 0; rr < 8; ++rr) {
            int r = rr * 8 + rA;
            int m = m0 + by * 64 + r;
            int k = k0 + kkA;
            float v;
            if (k < 128) v = X[((size_t)m * 8 + h) * 128 + k];
            else         v = A2[(size_t)m * 1024 + h * 128 + (k - 128)];
            As[kkA][r] = v;
        }
#pragma unroll
        for (int q = 0; q < 8; ++q) {
            int k = kB + q * 4;
            Bs[k][oB] = W[((size_t)h * 256 + k0 + k) * Nw + bx * 64 + oB];
        }
        __syncthreads();
#pragma unroll
        for (int kk = 0; kk < 32; ++kk) {
            float4 a = *(const float4*)&As[kk][ty * 4];
            float4 bv = *(const float4*)&Bs[kk][tx * 4];
            acc[0][0] = fmaf(a.x, bv.x, acc[0][0]); acc[0][1] = fmaf(a.x, bv.y, acc[0][1]);
            acc[0][2] = fmaf(a.x, bv.z, acc[0][2]); acc[0][3] = fmaf(a.x, bv.w, acc[0][3]);
            acc[1][0] = fmaf(a.y, bv.x, acc[1][0]); acc[1][1] = fmaf(a.y, bv.y, acc[1][1]);
            acc[1][2] = fmaf(a.y, bv.z, acc[1][2]); acc[1][3] = fmaf(a.y, bv.w, acc[1][3]);
            acc[2][0] = fmaf(a.z, bv.x, acc[2][0]); acc[2][1] = fmaf(a.z, bv.y, acc[2][1]);
            acc[2][2] = fmaf(a.z, bv.z, acc[2][2]); acc[2][3] = fmaf(a.z, bv.w, acc[2][3]);
            acc[3][0] = fmaf(a.w, bv.x, acc[3][0]); acc[3][1] = fmaf(a.w, bv.y, acc[3][1]);
            acc[3][2] = fmaf(a.w, bv.z, acc[3][2]); acc[3][3] = fmaf(a.w, bv.w, acc[3][3]);
        }
        __syncthreads();
    }
#pragma unroll
    for (int i = 0; i < 4; ++i) {
        int ml = by * 64 + ty * 4 + i;   // local row
        int o = bx * 64 + tx * 4;
        const float* bp = bias + (size_t)h * Nw + o;
        float4 ov;
        ov.x = acc[i][0] + bp[0];
        ov.y = acc[i][1] + bp[1];
        ov.z = acc[i][2] + bp[2];
        ov.w = acc[i][3] + bp[3];
        *(float4*)&OUT[((size_t)ml * 8 + h) * Nw + o] = ov;
    }
}

// ---- LN over (h,3,d) per row + gates; HID is chunk-local, FG/IG absolute ----
__global__ __launch_bounds__(256) void k_ln_gates(const float* __restrict__ HID, float* __restrict__ FG,
                                                  float* __restrict__ IG, const float* __restrict__ g,
                                                  const float* __restrict__ bb, int m0) {
    __shared__ float sm[3072];
    int bsl = blockIdx.x, t = threadIdx.x;
    int bs = m0 + bsl;
    const float4* row = (const float4*)(HID + (size_t)bsl * 3072);
    float s = 0.f, ss = 0.f;
#pragma unroll
    for (int p = 0; p < 3; ++p) {
        float4 v = row[p * 256 + t];
        ((float4*)sm)[p * 256 + t] = v;
        s += v.x + v.y + v.z + v.w;
        ss += v.x * v.x + v.y * v.y + v.z * v.z + v.w * v.w;
    }
    block_reduce2(s, ss);
    float m = s * (1.f / 3072.f);
    float var = ss * (1.f / 3072.f) - m * m;
    float r = rsqrtf(fmaxf(var, 0.f) + EPSF);
    int u0 = t * 4;
    int h = u0 >> 7;
    int d0 = u0 & 127;
    float fr[4], ir[4];
#pragma unroll
    for (int q = 0; q < 4; ++q) {
        int d = d0 + q;
        float yi = sm[h * 384 + d];
        float yf = sm[h * 384 + 128 + d];
        float yh = sm[h * 384 + 256 + d];
        float ni = (yi - m) * r * g[(h * 3 + 0) * 128 + d] + bb[(h * 3 + 0) * 128 + d];
        float nf = (yf - m) * r * g[(h * 3 + 1) * 128 + d] + bb[(h * 3 + 1) * 128 + d];
        float nh = (yh - m) * r * g[(h * 3 + 2) * 128 + d] + bb[(h * 3 + 2) * 128 + d];
        fr[q] = sigm(nf);
        ir[q] = sigm(ni) * fmaxf(nh, 0.f);
    }
    ((float4*)(FG + (size_t)bs * 1024))[t] = make_float4(fr[0], fr[1], fr[2], fr[3]);
    ((float4*)(IG + (size_t)bs * 1024))[t] = make_float4(ir[0], ir[1], ir[2], ir[3]);
}

// ---- LSTM scan c = f*c + i, chunked ----
__global__ __launch_bounds__(256) void k_scan_a(const float* __restrict__ FG, const float* __restrict__ IG,
                                                float* __restrict__ cF, float* __restrict__ cC) {
    int t = blockIdx.x * 256 + threadIdx.x;
    int d = t & 127, h = (t >> 7) & 7, k = (t >> 10) & 63, b = t >> 16;
    size_t base = (((size_t)(b * 4096 + k * 64)) * 8 + h) * 128 + d;
    float F = 1.f, Ca = 0.f;
    for (int j = 0; j < 64; ++j) {
        float f = FG[base + (size_t)j * 1024];
        float i = IG[base + (size_t)j * 1024];
        Ca = fmaf(f, Ca, i);
        F *= f;
    }
    size_t ci = (size_t)((b * 8 + h) * 128 + d) * 64 + k;
    cF[ci] = F;
    cC[ci] = Ca;
}

__global__ __launch_bounds__(256) void k_scan_b(const float* __restrict__ cF, const float* __restrict__ cC,
                                                const float* __restrict__ initcx, float* __restrict__ cI) {
    int ch = blockIdx.x * 256 + threadIdx.x;   // 4096
    float c = initcx[ch & 1023];
    size_t base = (size_t)ch * 64;
    for (int k = 0; k < 64; ++k) {
        cI[base + k] = c;
        c = fmaf(cF[base + k], c, cC[base + k]);
    }
}

__global__ __launch_bounds__(256) void k_scan_c(const float* __restrict__ FG, float* __restrict__ IGCELL,
                                                const float* __restrict__ cI) {
    int t = blockIdx.x * 256 + threadIdx.x;
    int d = t & 127, h = (t >> 7) & 7, k = (t >> 10) & 63, b = t >> 16;
    float c = cI[(size_t)((b * 8 + h) * 128 + d) * 64 + k];
    size_t base = (((size_t)(b * 4096 + k * 64)) * 8 + h) * 128 + d;
    for (int j = 0; j < 64; ++j) {
        float f = FG[base + (size_t)j * 1024];
        float i = IGCELL[base + (size_t)j * 1024];
        c = fmaf(f, c, i);
        IGCELL[base + (size_t)j * 1024] = c;
    }
}

// ---- final LN over (h,d) + sigmoid*cell -> out; OG chunk-local, CELL/OUT absolute ----
__global__ __launch_bounds__(256) void k_ln_out(const float* __restrict__ OG, const float* __restrict__ CELL,
                                                const float* __restrict__ g, const float* __restrict__ bb,
                                                float* __restrict__ OUT, int m0) {
    int bsl = blockIdx.x, t = threadIdx.x;
    int bs = m0 + bsl;
    const float4* row = (const float4*)(OG + (size_t)bsl * 1024);
    float4 v = row[t];
    float s = v.x + v.y + v.z + v.w;
    float ss = v.x * v.x + v.y * v.y + v.z * v.z + v.w * v.w;
    block_reduce2(s, ss);
    float m = s * (1.f / 1024.f);
    float var = ss * (1.f / 1024.f) - m * m;
    float r = rsqrtf(fmaxf(var, 0.f) + EPSF);
    float4 gv = ((const float4*)g)[t];
    float4 bv = ((const float4*)bb)[t];
    float4 cv = ((const float4*)(CELL + (size_t)bs * 1024))[t];
    float4 o;
    o.x = sigm((v.x - m) * r * gv.x + bv.x) * cv.x;
    o.y = sigm((v.y - m) * r * gv.y + bv.y) * cv.y;
    o.z = sigm((v.z - m) * r * gv.z + bv.z) * cv.z;
    o.w = sigm((v.w - m) * r * gv.w + bv.w) * cv.w;
    ((float4*)(OUT + (size_t)bs * 1024))[t] = o;
}

extern "C" void kernel_launch(void* const* d_in, const int* in_sizes, int n_in,
                              void* d_out, int out_size, void* d_ws, size_t ws_size,
                              hipStream_t stream) {
    const float* X      = (const float*)d_in[0];   // heads_input (B,S,H,D)
    const float* W_hid  = (const float*)d_in[1];   // (H,256,384)
    const float* b_hid  = (const float*)d_in[2];   // (H,384)
    const float* W_og   = (const float*)d_in[3];   // (H,256,128)
    const float* b_og   = (const float*)d_in[4];   // (H,128)
    const float* g_cs   = (const float*)d_in[5];
    const float* b_cs   = (const float*)d_in[6];
    const float* g_hid  = (const float*)d_in[7];
    const float* b_hidl = (const float*)d_in[8];
    const float* g_og   = (const float*)d_in[9];
    const float* b_ogl  = (const float*)d_in[10];
    const float* initcx = (const float*)d_in[11];

    float* ws = (float*)d_ws;
    // Persistent: R0 (csum -> fgate), R2 (igh -> cell), scan scratch.
    // Chunked: hidC holds CH rows of hid (CH*3072 f32), reused for og chunk (CH*1024 f32).
    const size_t NR0   = 16777216ull;   // 64 MB
    const size_t NR2   = 16777216ull;   // 64 MB
    const size_t NSC   = 262144ull;     // per scan-scratch array
    float* R0   = ws;
    float* R2   = ws + NR0;
    float* cS   = ws + NR0 + NR2;
    float* cO   = cS + NSC;
    float* cF   = cO + NSC;
    float* cC   = cF + NSC;
    float* cI   = cC + NSC;
    float* hidC = cI + NSC;             // offset 34,865,152 floats (139.46 MB)
    const size_t base_floats = 34865152ull;

    // Choose chunk rows CH (power of two, divides 16384) from available ws.
    size_t avail = ws_size / 4 > base_floats ? ws_size / 4 - base_floats : 0;
    int CH = 1024;
    for (int c = 16384; c >= 1024; c >>= 1) {
        if ((size_t)c * 3072ull <= avail) { CH = c; break; }
    }
    const int NC = 16384 / CH;

    dim3 blk(256);
    k_cumsum_a<<<1024, blk, 0, stream>>>(X, cS);
    k_cumsum_b<<<16, blk, 0, stream>>>(cS, cO);
    k_cumsum_c<<<1024, blk, 0, stream>>>(X, cO, R0);
    k_ln_csum<<<16384, blk, 0, stream>>>(R0, g_cs, b_cs);
    for (int c = 0; c < NC; ++c) {
        int m0 = c * CH;
        k_gemm<<<dim3(6, CH / 64, 8), blk, 0, stream>>>(X, R0, W_hid, b_hid, hidC, 384, m0);
        k_ln_gates<<<CH, blk, 0, stream>>>(hidC, R0, R2, g_hid, b_hidl, m0);
    }
    k_scan_a<<<1024, blk, 0, stream>>>(R0, R2, cF, cC);
    k_scan_b<<<16, blk, 0, stream>>>(cF, cC, initcx, cI);
    k_scan_c<<<1024, blk, 0, stream>>>(R0, R2, cI);
    for (int c = 0; c < NC; ++c) {
        int m0 = c * CH;
        k_gemm<<<dim3(2, CH / 64, 8), blk, 0, stream>>>(X, R2, W_og, b_og, hidC, 128, m0);
        k_ln_out<<<CH, blk, 0, stream>>>(hidC, R2, g_og, b_ogl, (float*)d_out, m0);
    }
}

// Round 6
// 370.022 us; speedup vs baseline: 2.2140x; 2.2140x over previous
//
#include <hip/hip_runtime.h>

#define EPSF 1e-6f

// Shapes: B=4, S=4096, H=8, D=128
// BS = 16384 rows; HD = 1024; ROW3 = 3072; channels = B*H*D = 4096
// Scan chunking: 64 chunks of length 64 along S.
// GEMMs: bf16 MFMA (16x16x32), A = [X | csum] or [X | cell], W pre-transposed to [h][o][k] bf16.

typedef __attribute__((ext_vector_type(8))) short short8v;
typedef __attribute__((ext_vector_type(4))) float float4v;

__device__ __forceinline__ float sigm(float x) { return 1.0f / (1.0f + __expf(-x)); }

__device__ __forceinline__ unsigned short f2bf(float f) {
    unsigned int u = __float_as_uint(f);
    u = (u + 0x7fffu + ((u >> 16) & 1u)) >> 16;   // RNE
    return (unsigned short)u;
}
__device__ __forceinline__ float bf2f_lo(unsigned int p) { return __uint_as_float(p << 16); }
__device__ __forceinline__ float bf2f_hi(unsigned int p) { return __uint_as_float(p & 0xffff0000u); }

// Block-wide (sum, sumsq) reduction; requires blockDim.x == 256.
__device__ __forceinline__ void block_reduce2(float& a, float& b) {
#pragma unroll
    for (int off = 32; off > 0; off >>= 1) {
        a += __shfl_down(a, off);
        b += __shfl_down(b, off);
    }
    __shared__ float sa[8], sb[8];
    int wid = threadIdx.x >> 6;
    int lane = threadIdx.x & 63;
    if (lane == 0) { sa[wid] = a; sb[wid] = b; }
    __syncthreads();
    a = sa[0] + sa[1] + sa[2] + sa[3];
    b = sb[0] + sb[1] + sb[2] + sb[3];
}

// ---- W transpose+cast: Wt[(h*Nw + o)*256 + k] = bf16(W[(h*256 + k)*Nw + o]) ----
__global__ __launch_bounds__(256) void k_prep_w(const float* __restrict__ W, unsigned short* __restrict__ Wt,
                                                int Nw) {
    int idx = blockIdx.x * 256 + threadIdx.x;    // 8*Nw*256 total
    int k = idx & 255;
    int rest = idx >> 8;                          // h*Nw + o
    int o = rest % Nw;
    int h = rest / Nw;
    Wt[idx] = f2bf(W[((size_t)h * 256 + k) * Nw + o]);
}

// ---- cumsum ----
__global__ __launch_bounds__(256) void k_cumsum_a(const float* __restrict__ X, float* __restrict__ cS) {
    int t = blockIdx.x * 256 + threadIdx.x;
    int d = t & 127, h = (t >> 7) & 7, k = (t >> 10) & 63, b = t >> 16;
    size_t base = (((size_t)(b * 4096 + k * 64)) * 8 + h) * 128 + d;
    float s = 0.f;
#pragma unroll 8
    for (int j = 0; j < 64; ++j) s += X[base + (size_t)j * 1024];
    cS[(size_t)((b * 8 + h) * 128 + d) * 64 + k] = s;
}

__global__ __launch_bounds__(256) void k_cumsum_b(const float* __restrict__ cS, float* __restrict__ cO) {
    int ch = blockIdx.x * 256 + threadIdx.x;
    size_t base = (size_t)ch * 64;
    float off = 0.f;
    for (int k = 0; k < 64; ++k) { float v = cS[base + k]; cO[base + k] = off; off += v; }
}

// pass C: write exclusive prefix; also emit Xb = bf16(X)
__global__ __launch_bounds__(256) void k_cumsum_c(const float* __restrict__ X, const float* __restrict__ cO,
                                                  float* __restrict__ CSUM, unsigned short* __restrict__ XB) {
    int t = blockIdx.x * 256 + threadIdx.x;
    int d = t & 127, h = (t >> 7) & 7, k = (t >> 10) & 63, b = t >> 16;
    int ch = (b * 8 + h) * 128 + d;
    float run = cO[(size_t)ch * 64 + k];
    size_t base = (((size_t)(b * 4096 + k * 64)) * 8 + h) * 128 + d;
    for (int j = 0; j < 64; ++j) {
        float x = X[base + (size_t)j * 1024];
        CSUM[base + (size_t)j * 1024] = run;
        XB[base + (size_t)j * 1024] = f2bf(x);
        run += x;
    }
}

// ---- LN over (h,d) per (b,s): reads f32 csum, writes bf16 normalized csum ----
__global__ __launch_bounds__(256) void k_ln_csum(const float* __restrict__ R0, unsigned short* __restrict__ CSB,
                                                 const float* __restrict__ g, const float* __restrict__ bb) {
    int bs = blockIdx.x, t = threadIdx.x;
    const float4* row = (const float4*)(R0 + (size_t)bs * 1024);
    float4 v = row[t];
    float s = v.x + v.y + v.z + v.w;
    float ss = v.x * v.x + v.y * v.y + v.z * v.z + v.w * v.w;
    block_reduce2(s, ss);
    float m = s * (1.f / 1024.f);
    float var = ss * (1.f / 1024.f) - m * m;
    float r = rsqrtf(fmaxf(var, 0.f) + EPSF);
    float4 gv = ((const float4*)g)[t];
    float4 bv = ((const float4*)bb)[t];
    ushort4 o;
    o.x = f2bf((v.x - m) * r * gv.x + bv.x);
    o.y = f2bf((v.y - m) * r * gv.y + bv.y);
    o.z = f2bf((v.z - m) * r * gv.z + bv.z);
    o.w = f2bf((v.w - m) * r * gv.w + bv.w);
    ((ushort4*)(CSB + (size_t)bs * 1024))[t] = o;
}

// ---- bf16 MFMA GEMM per head over a row-chunk ----
// C[ml, h, o] = bias[h,o] + sum_k cat[m,h,k]*W[h,k,o];  k-tile0 = A1 (X), k-tile1 = A2.
// A1/A2: bf16 (m,h,d) absolute rows; Wt: bf16 [h][o][k]; OUT: bf16 chunk-local [(ml*8+h)*Nw + o].
__global__ __launch_bounds__(256) void k_gemm_bf16(const unsigned short* __restrict__ A1,
                                                   const unsigned short* __restrict__ A2,
                                                   const unsigned short* __restrict__ Wt,
                                                   const float* __restrict__ bias,
                                                   unsigned short* __restrict__ OUT, int Nw, int m0) {
    __shared__ short As[16384];   // [128 rows][128 k] bf16, 16B-slot XOR-swizzled by (row&7)
    __shared__ short Bs[16384];   // [128 cols][128 k] bf16, same swizzle
    int h = blockIdx.z, by = blockIdx.y, bx = blockIdx.x;
    int t = threadIdx.x;
    int lane = t & 63, wid = t >> 6;
    int wr = wid >> 1, wc = wid & 1;       // wave -> 64x64 sub-tile
    int l15 = lane & 15, l4 = lane >> 4;
    float4v acc[4][4];
#pragma unroll
    for (int i = 0; i < 4; ++i)
#pragma unroll
        for (int j = 0; j < 4; ++j) acc[i][j] = (float4v)(0.f);

    const size_t mbase = (size_t)(m0 + by * 128);
    for (int ks = 0; ks < 2; ++ks) {
        const unsigned short* Asrc = ks ? A2 : A1;
        // stage A: wave wid covers LDS rows [wid*32, wid*32+32); 4 rows (1KB) per issue
#pragma unroll
        for (int it = 0; it < 8; ++it) {
            int r0 = wid * 32 + it * 4;
            int r = r0 + l4;
            size_t g = ((mbase + r) * 8 + h) * 128 + 8 * (l15 ^ (r & 7));   // pre-swizzled source
            __builtin_amdgcn_global_load_lds((const __attribute__((address_space(1))) void*)(Asrc + g),
                                             (__attribute__((address_space(3))) void*)(As + r0 * 128),
                                             16, 0, 0);
        }
        // stage B (Wt rows are 256 k; take 128-k slice ks)
#pragma unroll
        for (int it = 0; it < 8; ++it) {
            int n0 = wid * 32 + it * 4;
            int nl = n0 + l4;
            size_t g = ((size_t)(h * Nw + bx * 128 + nl)) * 256 + ks * 128 + 8 * (l15 ^ (nl & 7));
            __builtin_amdgcn_global_load_lds((const __attribute__((address_space(1))) void*)(Wt + g),
                                             (__attribute__((address_space(3))) void*)(Bs + n0 * 128),
                                             16, 0, 0);
        }
        asm volatile("s_waitcnt vmcnt(0)" ::: "memory");
        __syncthreads();
#pragma unroll
        for (int kk = 0; kk < 4; ++kk) {
            short8v a[4], b[4];
#pragma unroll
            for (int i = 0; i < 4; ++i) {
                int r = wr * 64 + i * 16 + l15;
                int slot = (kk * 4 + l4) ^ (r & 7);
                a[i] = *(const short8v*)(As + r * 128 + slot * 8);
            }
#pragma unroll
            for (int j = 0; j < 4; ++j) {
                int c = wc * 64 + j * 16 + l15;
                int slot = (kk * 4 + l4) ^ (c & 7);
                b[j] = *(const short8v*)(Bs + c * 128 + slot * 8);
            }
#pragma unroll
            for (int i = 0; i < 4; ++i)
#pragma unroll
                for (int j = 0; j < 4; ++j)
                    acc[i][j] = __builtin_amdgcn_mfma_f32_16x16x32_bf16(a[i], b[j], acc[i][j], 0, 0, 0);
        }
        __syncthreads();   // LDS consumed; safe to restage
    }
    // epilogue: bias + cvt bf16; C/D: col = lane&15, row = (lane>>4)*4 + q
#pragma unroll
    for (int j = 0; j < 4; ++j) {
        int o = bx * 128 + wc * 64 + j * 16 + l15;
        float bv = bias[h * Nw + o];
#pragma unroll
        for (int i = 0; i < 4; ++i) {
            int mlb = by * 128 + wr * 64 + i * 16 + l4 * 4;
#pragma unroll
            for (int q = 0; q < 4; ++q) {
                OUT[((size_t)(mlb + q) * 8 + h) * Nw + o] = f2bf(acc[i][j][q] + bv);
            }
        }
    }
}

// ---- LN over (h,3,d) per row + gates; HID bf16 chunk-local, FG/IG f32 absolute ----
__global__ __launch_bounds__(256) void k_ln_gates(const unsigned short* __restrict__ HID,
                                                  float* __restrict__ FG, float* __restrict__ IG,
                                                  const float* __restrict__ g, const float* __restrict__ bb,
                                                  int m0) {
    __shared__ float sm[3072];
    int bsl = blockIdx.x, t = threadIdx.x;
    int bs = m0 + bsl;
    const uint4* row = (const uint4*)(HID + (size_t)bsl * 3072);   // 384 x 8 bf16
    float s = 0.f, ss = 0.f;
    for (int idx = t; idx < 384; idx += 256) {
        uint4 u = row[idx];
        float f0 = bf2f_lo(u.x), f1 = bf2f_hi(u.x);
        float f2 = bf2f_lo(u.y), f3 = bf2f_hi(u.y);
        float f4 = bf2f_lo(u.z), f5 = bf2f_hi(u.z);
        float f6 = bf2f_lo(u.w), f7 = bf2f_hi(u.w);
        float* p = sm + idx * 8;
        p[0] = f0; p[1] = f1; p[2] = f2; p[3] = f3; p[4] = f4; p[5] = f5; p[6] = f6; p[7] = f7;
        s += f0 + f1 + f2 + f3 + f4 + f5 + f6 + f7;
        ss += f0 * f0 + f1 * f1 + f2 * f2 + f3 * f3 + f4 * f4 + f5 * f5 + f6 * f6 + f7 * f7;
    }
    block_reduce2(s, ss);
    float m = s * (1.f / 3072.f);
    float var = ss * (1.f / 3072.f) - m * m;
    float r = rsqrtf(fmaxf(var, 0.f) + EPSF);
    int u0 = t * 4;
    int h = u0 >> 7;
    int d0 = u0 & 127;
    float fr[4], ir[4];
#pragma unroll
    for (int q = 0; q < 4; ++q) {
        int d = d0 + q;
        float yi = sm[h * 384 + d];
        float yf = sm[h * 384 + 128 + d];
        float yh = sm[h * 384 + 256 + d];
        float ni = (yi - m) * r * g[(h * 3 + 0) * 128 + d] + bb[(h * 3 + 0) * 128 + d];
        float nf = (yf - m) * r * g[(h * 3 + 1) * 128 + d] + bb[(h * 3 + 1) * 128 + d];
        float nh = (yh - m) * r * g[(h * 3 + 2) * 128 + d] + bb[(h * 3 + 2) * 128 + d];
        fr[q] = sigm(nf);
        ir[q] = sigm(ni) * fmaxf(nh, 0.f);
    }
    ((float4*)(FG + (size_t)bs * 1024))[t] = make_float4(fr[0], fr[1], fr[2], fr[3]);
    ((float4*)(IG + (size_t)bs * 1024))[t] = make_float4(ir[0], ir[1], ir[2], ir[3]);
}

// ---- LSTM scan ----
__global__ __launch_bounds__(256) void k_scan_a(const float* __restrict__ FG, const float* __restrict__ IG,
                                                float* __restrict__ cF, float* __restrict__ cC) {
    int t = blockIdx.x * 256 + threadIdx.x;
    int d = t & 127, h = (t >> 7) & 7, k = (t >> 10) & 63, b = t >> 16;
    size_t base = (((size_t)(b * 4096 + k * 64)) * 8 + h) * 128 + d;
    float F = 1.f, Ca = 0.f;
    for (int j = 0; j < 64; ++j) {
        float f = FG[base + (size_t)j * 1024];
        float i = IG[base + (size_t)j * 1024];
        Ca = fmaf(f, Ca, i);
        F *= f;
    }
    size_t ci = (size_t)((b * 8 + h) * 128 + d) * 64 + k;
    cF[ci] = F;
    cC[ci] = Ca;
}

__global__ __launch_bounds__(256) void k_scan_b(const float* __restrict__ cF, const float* __restrict__ cC,
                                                const float* __restrict__ initcx, float* __restrict__ cI) {
    int ch = blockIdx.x * 256 + threadIdx.x;
    float c = initcx[ch & 1023];
    size_t base = (size_t)ch * 64;
    for (int k = 0; k < 64; ++k) {
        cI[base + k] = c;
        c = fmaf(cF[base + k], c, cC[base + k]);
    }
}

// final pass: cell overwrites IG in place (f32) and also emits bf16 cell
__global__ __launch_bounds__(256) void k_scan_c(const float* __restrict__ FG, float* __restrict__ IGCELL,
                                                const float* __restrict__ cI, unsigned short* __restrict__ CLB) {
    int t = blockIdx.x * 256 + threadIdx.x;
    int d = t & 127, h = (t >> 7) & 7, k = (t >> 10) & 63, b = t >> 16;
    float c = cI[(size_t)((b * 8 + h) * 128 + d) * 64 + k];
    size_t base = (((size_t)(b * 4096 + k * 64)) * 8 + h) * 128 + d;
    for (int j = 0; j < 64; ++j) {
        float f = FG[base + (size_t)j * 1024];
        float i = IGCELL[base + (size_t)j * 1024];
        c = fmaf(f, c, i);
        IGCELL[base + (size_t)j * 1024] = c;
        CLB[base + (size_t)j * 1024] = f2bf(c);
    }
}

// ---- final LN over (h,d) + sigmoid*cell -> out; OG bf16 chunk-local, CELL f32/OUT absolute ----
__global__ __launch_bounds__(256) void k_ln_out(const unsigned short* __restrict__ OG,
                                                const float* __restrict__ CELL,
                                                const float* __restrict__ g, const float* __restrict__ bb,
                                                float* __restrict__ OUT, int m0) {
    int bsl = blockIdx.x, t = threadIdx.x;
    int bs = m0 + bsl;
    uint2 u = ((const uint2*)(OG + (size_t)bsl * 1024))[t];
    float4 v;
    v.x = bf2f_lo(u.x); v.y = bf2f_hi(u.x);
    v.z = bf2f_lo(u.y); v.w = bf2f_hi(u.y);
    float s = v.x + v.y + v.z + v.w;
    float ss = v.x * v.x + v.y * v.y + v.z * v.z + v.w * v.w;
    block_reduce2(s, ss);
    float m = s * (1.f / 1024.f);
    float var = ss * (1.f / 1024.f) - m * m;
    float r = rsqrtf(fmaxf(var, 0.f) + EPSF);
    float4 gv = ((const float4*)g)[t];
    float4 bv = ((const float4*)bb)[t];
    float4 cv = ((const float4*)(CELL + (size_t)bs * 1024))[t];
    float4 o;
    o.x = sigm((v.x - m) * r * gv.x + bv.x) * cv.x;
    o.y = sigm((v.y - m) * r * gv.y + bv.y) * cv.y;
    o.z = sigm((v.z - m) * r * gv.z + bv.z) * cv.z;
    o.w = sigm((v.w - m) * r * gv.w + bv.w) * cv.w;
    ((float4*)(OUT + (size_t)bs * 1024))[t] = o;
}

extern "C" void kernel_launch(void* const* d_in, const int* in_sizes, int n_in,
                              void* d_out, int out_size, void* d_ws, size_t ws_size,
                              hipStream_t stream) {
    const float* X      = (const float*)d_in[0];
    const float* W_hid  = (const float*)d_in[1];
    const float* b_hid  = (const float*)d_in[2];
    const float* W_og   = (const float*)d_in[3];
    const float* b_og   = (const float*)d_in[4];
    const float* g_cs   = (const float*)d_in[5];
    const float* b_cs   = (const float*)d_in[6];
    const float* g_hid  = (const float*)d_in[7];
    const float* b_hidl = (const float*)d_in[8];
    const float* g_og   = (const float*)d_in[9];
    const float* b_ogl  = (const float*)d_in[10];
    const float* initcx = (const float*)d_in[11];

    float* ws = (float*)d_ws;
    // float-offset layout
    const size_t O_R0   = 0ull;          // csum f32 -> FG f32 (16,777,216)
    const size_t O_R2   = 16777216ull;   // IG -> cell f32 (16,777,216)
    const size_t O_CS   = 33554432ull;   // 5 scan scratch arrays of 262,144
    const size_t O_XB   = 34865152ull;   // Xb bf16 (16.78M elems = 8,388,608 floats)
    const size_t O_CSB  = 43253760ull;   // csum bf16
    const size_t O_CLB  = 51642368ull;   // cell bf16
    const size_t O_WTH  = 60030976ull;   // Wt_hid bf16 (786,432 elems = 393,216 floats)
    const size_t O_WTO  = 60424192ull;   // Wt_og bf16 (262,144 elems = 131,072 floats)
    const size_t O_HID  = 60555264ull;   // hid/og bf16 chunk buffer (CH*3072 elems = CH*1536 floats)

    float* R0   = ws + O_R0;
    float* R2   = ws + O_R2;
    float* cS   = ws + O_CS;
    float* cO   = cS + 262144;
    float* cF   = cO + 262144;
    float* cC   = cF + 262144;
    float* cI   = cC + 262144;
    unsigned short* XB   = (unsigned short*)(ws + O_XB);
    unsigned short* CSB  = (unsigned short*)(ws + O_CSB);
    unsigned short* CLB  = (unsigned short*)(ws + O_CLB);
    unsigned short* WTH  = (unsigned short*)(ws + O_WTH);
    unsigned short* WTO  = (unsigned short*)(ws + O_WTO);
    unsigned short* HIDC = (unsigned short*)(ws + O_HID);

    // chunk rows CH (pow2, multiple of 128) from available ws
    size_t avail = (ws_size / 4 > O_HID) ? ws_size / 4 - O_HID : 0;
    int CH = 1024;
    for (int c = 16384; c >= 1024; c >>= 1) {
        if ((size_t)c * 1536ull <= avail) { CH = c; break; }
    }
    const int NC = 16384 / CH;

    dim3 blk(256);
    k_prep_w<<<3072, blk, 0, stream>>>(W_hid, WTH, 384);
    k_prep_w<<<1024, blk, 0, stream>>>(W_og, WTO, 128);
    k_cumsum_a<<<1024, blk, 0, stream>>>(X, cS);
    k_cumsum_b<<<16, blk, 0, stream>>>(cS, cO);
    k_cumsum_c<<<1024, blk, 0, stream>>>(X, cO, R0, XB);
    k_ln_csum<<<16384, blk, 0, stream>>>(R0, CSB, g_cs, b_cs);
    for (int c = 0; c < NC; ++c) {
        int m0 = c * CH;
        k_gemm_bf16<<<dim3(3, CH / 128, 8), blk, 0, stream>>>(XB, CSB, WTH, b_hid, HIDC, 384, m0);
        k_ln_gates<<<CH, blk, 0, stream>>>(HIDC, R0, R2, g_hid, b_hidl, m0);
    }
    k_scan_a<<<1024, blk, 0, stream>>>(R0, R2, cF, cC);
    k_scan_b<<<16, blk, 0, stream>>>(cF, cC, initcx, cI);
    k_scan_c<<<1024, blk, 0, stream>>>(R0, R2, cI, CLB);
    for (int c = 0; c < NC; ++c) {
        int m0 = c * CH;
        k_gemm_bf16<<<dim3(1, CH / 128, 8), blk, 0, stream>>>(XB, CLB, WTO, b_og, HIDC, 128, m0);
        k_ln_out<<<CH, blk, 0, stream>>>(HIDC, R2, g_og, b_ogl, (float*)d_out, m0);
    }
}

// Round 7
// 257.502 us; speedup vs baseline: 3.1815x; 1.4370x over previous
//
#include <hip/hip_runtime.h>

#define EPSF 1e-6f

// Shapes: B=4, S=4096, H=8, D=128
// BS = 16384 rows; HD = 1024; ROW3 = 3072; channels = B*H*D = 4096
// All large intermediates bf16 (storage only; math f32). Scan chunking: 64x64 along S.

typedef __attribute__((ext_vector_type(8))) short short8v;
typedef __attribute__((ext_vector_type(4))) float float4v;

__device__ __forceinline__ float sigm(float x) { return 1.0f / (1.0f + __expf(-x)); }

__device__ __forceinline__ unsigned short f2bf(float f) {
    unsigned int u = __float_as_uint(f);
    u = (u + 0x7fffu + ((u >> 16) & 1u)) >> 16;   // RNE
    return (unsigned short)u;
}
__device__ __forceinline__ float bf2f(unsigned short s) { return __uint_as_float(((unsigned int)s) << 16); }
__device__ __forceinline__ float bf2f_lo(unsigned int p) { return __uint_as_float(p << 16); }
__device__ __forceinline__ float bf2f_hi(unsigned int p) { return __uint_as_float(p & 0xffff0000u); }
__device__ __forceinline__ unsigned int pack2bf(float a, float b) {
    return (unsigned int)f2bf(a) | ((unsigned int)f2bf(b) << 16);
}

// Block-wide (sum, sumsq) reduction; requires blockDim.x == 256.
__device__ __forceinline__ void block_reduce2(float& a, float& b) {
#pragma unroll
    for (int off = 32; off > 0; off >>= 1) {
        a += __shfl_down(a, off);
        b += __shfl_down(b, off);
    }
    __shared__ float sa[8], sb[8];
    int wid = threadIdx.x >> 6;
    int lane = threadIdx.x & 63;
    if (lane == 0) { sa[wid] = a; sb[wid] = b; }
    __syncthreads();
    a = sa[0] + sa[1] + sa[2] + sa[3];
    b = sb[0] + sb[1] + sb[2] + sb[3];
}

// ---- W transpose+cast: Wt[(h*Nw + o)*256 + k] = bf16(W[(h*256 + k)*Nw + o]) ----
__global__ __launch_bounds__(256) void k_prep_w(const float* __restrict__ W, unsigned short* __restrict__ Wt,
                                                int Nw) {
    int idx = blockIdx.x * 256 + threadIdx.x;
    int k = idx & 255;
    int rest = idx >> 8;
    int o = rest % Nw;
    int h = rest / Nw;
    Wt[idx] = f2bf(W[((size_t)h * 256 + k) * Nw + o]);
}

// ---- cumsum pass A: chunk sums (from bf16-rounded x, consistent with pass C) + emit XB ----
__global__ __launch_bounds__(256) void k_cumsum_a(const float* __restrict__ X, float* __restrict__ cS,
                                                  unsigned short* __restrict__ XB) {
    int t = blockIdx.x * 256 + threadIdx.x;          // 262144
    int d = t & 127, h = (t >> 7) & 7, k = (t >> 10) & 63, b = t >> 16;
    size_t base = (((size_t)(b * 4096 + k * 64)) * 8 + h) * 128 + d;
    float s = 0.f;
    for (int j = 0; j < 64; ++j) {
        unsigned short xb = f2bf(X[base + (size_t)j * 1024]);
        XB[base + (size_t)j * 1024] = xb;
        s += bf2f(xb);
    }
    cS[(size_t)((b * 8 + h) * 128 + d) * 64 + k] = s;
}

__global__ __launch_bounds__(256) void k_cumsum_b(const float* __restrict__ cS, float* __restrict__ cO) {
    int ch = blockIdx.x * 256 + threadIdx.x;          // 4096
    size_t base = (size_t)ch * 64;
    float off = 0.f;
    for (int k = 0; k < 64; ++k) { float v = cS[base + k]; cO[base + k] = off; off += v; }
}

// pass C: exclusive prefix from XB, stored bf16
__global__ __launch_bounds__(256) void k_cumsum_c(const unsigned short* __restrict__ XB,
                                                  const float* __restrict__ cO,
                                                  unsigned short* __restrict__ CSUMB) {
    int t = blockIdx.x * 256 + threadIdx.x;
    int d = t & 127, h = (t >> 7) & 7, k = (t >> 10) & 63, b = t >> 16;
    int ch = (b * 8 + h) * 128 + d;
    float run = cO[(size_t)ch * 64 + k];
    size_t base = (((size_t)(b * 4096 + k * 64)) * 8 + h) * 128 + d;
    for (int j = 0; j < 64; ++j) {
        float x = bf2f(XB[base + (size_t)j * 1024]);
        CSUMB[base + (size_t)j * 1024] = f2bf(run);
        run += x;
    }
}

// ---- LN over (h,d) per (b,s): bf16 in, bf16 out ----
__global__ __launch_bounds__(256) void k_ln_csum(const unsigned short* __restrict__ CSUMB,
                                                 unsigned short* __restrict__ CSB,
                                                 const float* __restrict__ g, const float* __restrict__ bb) {
    int bs = blockIdx.x, t = threadIdx.x;
    uint2 u = ((const uint2*)(CSUMB + (size_t)bs * 1024))[t];
    float4 v;
    v.x = bf2f_lo(u.x); v.y = bf2f_hi(u.x);
    v.z = bf2f_lo(u.y); v.w = bf2f_hi(u.y);
    float s = v.x + v.y + v.z + v.w;
    float ss = v.x * v.x + v.y * v.y + v.z * v.z + v.w * v.w;
    block_reduce2(s, ss);
    float m = s * (1.f / 1024.f);
    float var = ss * (1.f / 1024.f) - m * m;
    float r = rsqrtf(fmaxf(var, 0.f) + EPSF);
    float4 gv = ((const float4*)g)[t];
    float4 bv = ((const float4*)bb)[t];
    uint2 o;
    o.x = pack2bf((v.x - m) * r * gv.x + bv.x, (v.y - m) * r * gv.y + bv.y);
    o.y = pack2bf((v.z - m) * r * gv.z + bv.z, (v.w - m) * r * gv.w + bv.w);
    ((uint2*)(CSB + (size_t)bs * 1024))[t] = o;
}

// ---- bf16 MFMA GEMM per head over a row-chunk (unchanged structure) ----
__global__ __launch_bounds__(256) void k_gemm_bf16(const unsigned short* __restrict__ A1,
                                                   const unsigned short* __restrict__ A2,
                                                   const unsigned short* __restrict__ Wt,
                                                   const float* __restrict__ bias,
                                                   unsigned short* __restrict__ OUT, int Nw, int m0) {
    __shared__ short As[16384];   // [128 rows][128 k] bf16, 16B-slot XOR-swizzled by (row&7)
    __shared__ short Bs[16384];
    int h = blockIdx.z, by = blockIdx.y, bx = blockIdx.x;
    int t = threadIdx.x;
    int lane = t & 63, wid = t >> 6;
    int wr = wid >> 1, wc = wid & 1;
    int l15 = lane & 15, l4 = lane >> 4;
    float4v acc[4][4];
#pragma unroll
    for (int i = 0; i < 4; ++i)
#pragma unroll
        for (int j = 0; j < 4; ++j) acc[i][j] = (float4v)(0.f);

    const size_t mbase = (size_t)(m0 + by * 128);
    for (int ks = 0; ks < 2; ++ks) {
        const unsigned short* Asrc = ks ? A2 : A1;
#pragma unroll
        for (int it = 0; it < 8; ++it) {
            int r0 = wid * 32 + it * 4;
            int r = r0 + l4;
            size_t g = ((mbase + r) * 8 + h) * 128 + 8 * (l15 ^ (r & 7));
            __builtin_amdgcn_global_load_lds((const __attribute__((address_space(1))) void*)(Asrc + g),
                                             (__attribute__((address_space(3))) void*)(As + r0 * 128),
                                             16, 0, 0);
        }
#pragma unroll
        for (int it = 0; it < 8; ++it) {
            int n0 = wid * 32 + it * 4;
            int nl = n0 + l4;
            size_t g = ((size_t)(h * Nw + bx * 128 + nl)) * 256 + ks * 128 + 8 * (l15 ^ (nl & 7));
            __builtin_amdgcn_global_load_lds((const __attribute__((address_space(1))) void*)(Wt + g),
                                             (__attribute__((address_space(3))) void*)(Bs + n0 * 128),
                                             16, 0, 0);
        }
        asm volatile("s_waitcnt vmcnt(0)" ::: "memory");
        __syncthreads();
#pragma unroll
        for (int kk = 0; kk < 4; ++kk) {
            short8v a[4], b[4];
#pragma unroll
            for (int i = 0; i < 4; ++i) {
                int r = wr * 64 + i * 16 + l15;
                int slot = (kk * 4 + l4) ^ (r & 7);
                a[i] = *(const short8v*)(As + r * 128 + slot * 8);
            }
#pragma unroll
            for (int j = 0; j < 4; ++j) {
                int c = wc * 64 + j * 16 + l15;
                int slot = (kk * 4 + l4) ^ (c & 7);
                b[j] = *(const short8v*)(Bs + c * 128 + slot * 8);
            }
#pragma unroll
            for (int i = 0; i < 4; ++i)
#pragma unroll
                for (int j = 0; j < 4; ++j)
                    acc[i][j] = __builtin_amdgcn_mfma_f32_16x16x32_bf16(a[i], b[j], acc[i][j], 0, 0, 0);
        }
        __syncthreads();
    }
#pragma unroll
    for (int j = 0; j < 4; ++j) {
        int o = bx * 128 + wc * 64 + j * 16 + l15;
        float bv = bias[h * Nw + o];
#pragma unroll
        for (int i = 0; i < 4; ++i) {
            int mlb = by * 128 + wr * 64 + i * 16 + l4 * 4;
#pragma unroll
            for (int q = 0; q < 4; ++q) {
                OUT[((size_t)(mlb + q) * 8 + h) * Nw + o] = f2bf(acc[i][j][q] + bv);
            }
        }
    }
}

// ---- LN over (h,3,d) + gates; HID bf16 chunk-local; FG/IG bf16 absolute ----
__global__ __launch_bounds__(256) void k_ln_gates(const unsigned short* __restrict__ HID,
                                                  unsigned short* __restrict__ FG,
                                                  unsigned short* __restrict__ IG,
                                                  const float* __restrict__ g, const float* __restrict__ bb,
                                                  int m0) {
    __shared__ float sm[3072];
    int bsl = blockIdx.x, t = threadIdx.x;
    int bs = m0 + bsl;
    const uint4* row = (const uint4*)(HID + (size_t)bsl * 3072);
    float s = 0.f, ss = 0.f;
    for (int idx = t; idx < 384; idx += 256) {
        uint4 u = row[idx];
        float f0 = bf2f_lo(u.x), f1 = bf2f_hi(u.x);
        float f2 = bf2f_lo(u.y), f3 = bf2f_hi(u.y);
        float f4 = bf2f_lo(u.z), f5 = bf2f_hi(u.z);
        float f6 = bf2f_lo(u.w), f7 = bf2f_hi(u.w);
        float* p = sm + idx * 8;
        p[0] = f0; p[1] = f1; p[2] = f2; p[3] = f3; p[4] = f4; p[5] = f5; p[6] = f6; p[7] = f7;
        s += f0 + f1 + f2 + f3 + f4 + f5 + f6 + f7;
        ss += f0 * f0 + f1 * f1 + f2 * f2 + f3 * f3 + f4 * f4 + f5 * f5 + f6 * f6 + f7 * f7;
    }
    block_reduce2(s, ss);
    float m = s * (1.f / 3072.f);
    float var = ss * (1.f / 3072.f) - m * m;
    float r = rsqrtf(fmaxf(var, 0.f) + EPSF);
    int u0 = t * 4;
    int h = u0 >> 7;
    int d0 = u0 & 127;
    float fr[4], ir[4];
#pragma unroll
    for (int q = 0; q < 4; ++q) {
        int d = d0 + q;
        float yi = sm[h * 384 + d];
        float yf = sm[h * 384 + 128 + d];
        float yh = sm[h * 384 + 256 + d];
        float ni = (yi - m) * r * g[(h * 3 + 0) * 128 + d] + bb[(h * 3 + 0) * 128 + d];
        float nf = (yf - m) * r * g[(h * 3 + 1) * 128 + d] + bb[(h * 3 + 1) * 128 + d];
        float nh = (yh - m) * r * g[(h * 3 + 2) * 128 + d] + bb[(h * 3 + 2) * 128 + d];
        fr[q] = sigm(nf);
        ir[q] = sigm(ni) * fmaxf(nh, 0.f);
    }
    uint2 fo, io;
    fo.x = pack2bf(fr[0], fr[1]); fo.y = pack2bf(fr[2], fr[3]);
    io.x = pack2bf(ir[0], ir[1]); io.y = pack2bf(ir[2], ir[3]);
    ((uint2*)(FG + (size_t)bs * 1024))[t] = fo;
    ((uint2*)(IG + (size_t)bs * 1024))[t] = io;
}

// ---- LSTM scan over bf16 gates; 2 channels per thread ----
__global__ __launch_bounds__(256) void k_scan_a(const unsigned short* __restrict__ FG,
                                                const unsigned short* __restrict__ IG,
                                                float* __restrict__ cF, float* __restrict__ cC) {
    int t = blockIdx.x * 256 + threadIdx.x;    // 131072
    int d2 = t & 63, h = (t >> 6) & 7, k = (t >> 9) & 63, b = t >> 15;
    size_t base = (((size_t)(b * 4096 + k * 64)) * 8 + h) * 64 + d2;   // uint index
    const unsigned int* FGu = (const unsigned int*)FG;
    const unsigned int* IGu = (const unsigned int*)IG;
    float F0 = 1.f, C0 = 0.f, F1 = 1.f, C1 = 0.f;
    for (int j = 0; j < 64; ++j) {
        unsigned int fg = FGu[base + (size_t)j * 512];
        unsigned int ig = IGu[base + (size_t)j * 512];
        float f0 = bf2f_lo(fg), f1 = bf2f_hi(fg);
        C0 = fmaf(f0, C0, bf2f_lo(ig)); F0 *= f0;
        C1 = fmaf(f1, C1, bf2f_hi(ig)); F1 *= f1;
    }
    size_t ci0 = ((size_t)((b * 8 + h) * 128 + d2 * 2)) * 64 + k;
    cF[ci0] = F0; cC[ci0] = C0;
    cF[ci0 + 64] = F1; cC[ci0 + 64] = C1;
}

__global__ __launch_bounds__(256) void k_scan_b(const float* __restrict__ cF, const float* __restrict__ cC,
                                                const float* __restrict__ initcx, float* __restrict__ cI) {
    int ch = blockIdx.x * 256 + threadIdx.x;   // 4096
    float c = initcx[ch & 1023];
    size_t base = (size_t)ch * 64;
    for (int k = 0; k < 64; ++k) {
        cI[base + k] = c;
        c = fmaf(cF[base + k], c, cC[base + k]);
    }
}

// final pass: cell (bf16) overwrites IG in place
__global__ __launch_bounds__(256) void k_scan_c(const unsigned short* __restrict__ FG,
                                                unsigned short* __restrict__ IGCLB,
                                                const float* __restrict__ cI) {
    int t = blockIdx.x * 256 + threadIdx.x;    // 131072
    int d2 = t & 63, h = (t >> 6) & 7, k = (t >> 9) & 63, b = t >> 15;
    size_t base = (((size_t)(b * 4096 + k * 64)) * 8 + h) * 64 + d2;
    const unsigned int* FGu = (const unsigned int*)FG;
    unsigned int* IGu = (unsigned int*)IGCLB;
    size_t ci0 = ((size_t)((b * 8 + h) * 128 + d2 * 2)) * 64 + k;
    float c0 = cI[ci0], c1 = cI[ci0 + 64];
    for (int j = 0; j < 64; ++j) {
        unsigned int fg = FGu[base + (size_t)j * 512];
        unsigned int ig = IGu[base + (size_t)j * 512];
        c0 = fmaf(bf2f_lo(fg), c0, bf2f_lo(ig));
        c1 = fmaf(bf2f_hi(fg), c1, bf2f_hi(ig));
        IGu[base + (size_t)j * 512] = pack2bf(c0, c1);
    }
}

// ---- final LN over (h,d) + sigmoid*cell -> out; OG bf16 chunk-local, CLB bf16 absolute ----
__global__ __launch_bounds__(256) void k_ln_out(const unsigned short* __restrict__ OG,
                                                const unsigned short* __restrict__ CLB,
                                                const float* __restrict__ g, const float* __restrict__ bb,
                                                float* __restrict__ OUT, int m0) {
    int bsl = blockIdx.x, t = threadIdx.x;
    int bs = m0 + bsl;
    uint2 u = ((const uint2*)(OG + (size_t)bsl * 1024))[t];
    float4 v;
    v.x = bf2f_lo(u.x); v.y = bf2f_hi(u.x);
    v.z = bf2f_lo(u.y); v.w = bf2f_hi(u.y);
    float s = v.x + v.y + v.z + v.w;
    float ss = v.x * v.x + v.y * v.y + v.z * v.z + v.w * v.w;
    block_reduce2(s, ss);
    float m = s * (1.f / 1024.f);
    float var = ss * (1.f / 1024.f) - m * m;
    float r = rsqrtf(fmaxf(var, 0.f) + EPSF);
    float4 gv = ((const float4*)g)[t];
    float4 bv = ((const float4*)bb)[t];
    uint2 cu = ((const uint2*)(CLB + (size_t)bs * 1024))[t];
    float4 cv;
    cv.x = bf2f_lo(cu.x); cv.y = bf2f_hi(cu.x);
    cv.z = bf2f_lo(cu.y); cv.w = bf2f_hi(cu.y);
    float4 o;
    o.x = sigm((v.x - m) * r * gv.x + bv.x) * cv.x;
    o.y = sigm((v.y - m) * r * gv.y + bv.y) * cv.y;
    o.z = sigm((v.z - m) * r * gv.z + bv.z) * cv.z;
    o.w = sigm((v.w - m) * r * gv.w + bv.w) * cv.w;
    ((float4*)(OUT + (size_t)bs * 1024))[t] = o;
}

extern "C" void kernel_launch(void* const* d_in, const int* in_sizes, int n_in,
                              void* d_out, int out_size, void* d_ws, size_t ws_size,
                              hipStream_t stream) {
    const float* X      = (const float*)d_in[0];
    const float* W_hid  = (const float*)d_in[1];
    const float* b_hid  = (const float*)d_in[2];
    const float* W_og   = (const float*)d_in[3];
    const float* b_og   = (const float*)d_in[4];
    const float* g_cs   = (const float*)d_in[5];
    const float* b_cs   = (const float*)d_in[6];
    const float* g_hid  = (const float*)d_in[7];
    const float* b_hidl = (const float*)d_in[8];
    const float* g_og   = (const float*)d_in[9];
    const float* b_ogl  = (const float*)d_in[10];
    const float* initcx = (const float*)d_in[11];

    float* ws = (float*)d_ws;
    // float-offset layout (all bf16 arrays 16,777,216 elems = 8,388,608 floats)
    const size_t O_SC    = 0ull;           // cS,cO,cF,cC,cI: 5 x 262,144 f32
    const size_t O_XB    = 1310720ull;     // XB bf16
    const size_t O_CSUMB = 9699328ull;     // CSUMB bf16; aliased as FGB after ln_csum
    const size_t O_CSB   = 18087936ull;    // CSB bf16
    const size_t O_IGB   = 26476544ull;    // IGB bf16; overwritten in place by cell (CLB)
    const size_t O_WTH   = 34865152ull;    // Wt_hid bf16 (786,432 elems)
    const size_t O_WTO   = 35258368ull;    // Wt_og bf16 (262,144 elems)
    const size_t O_HID   = 35389440ull;    // HIDC bf16 chunk buffer (CH*3072 elems = CH*1536 floats)

    float* cS = ws + O_SC;
    float* cO = cS + 262144;
    float* cF = cO + 262144;
    float* cC = cF + 262144;
    float* cI = cC + 262144;
    unsigned short* XB    = (unsigned short*)(ws + O_XB);
    unsigned short* CSUMB = (unsigned short*)(ws + O_CSUMB);
    unsigned short* FGB   = CSUMB;          // alias: CSUMB dead after ln_csum
    unsigned short* CSB   = (unsigned short*)(ws + O_CSB);
    unsigned short* IGB   = (unsigned short*)(ws + O_IGB);
    unsigned short* CLB   = IGB;            // scan_c overwrites IG with cell in place
    unsigned short* WTH   = (unsigned short*)(ws + O_WTH);
    unsigned short* WTO   = (unsigned short*)(ws + O_WTO);
    unsigned short* HIDC  = (unsigned short*)(ws + O_HID);

    size_t avail = (ws_size / 4 > O_HID) ? ws_size / 4 - O_HID : 0;
    int CH = 1024;
    for (int c = 16384; c >= 1024; c >>= 1) {
        if ((size_t)c * 1536ull <= avail) { CH = c; break; }
    }
    const int NC = 16384 / CH;

    dim3 blk(256);
    k_prep_w<<<3072, blk, 0, stream>>>(W_hid, WTH, 384);
    k_prep_w<<<1024, blk, 0, stream>>>(W_og, WTO, 128);
    k_cumsum_a<<<1024, blk, 0, stream>>>(X, cS, XB);
    k_cumsum_b<<<16, blk, 0, stream>>>(cS, cO);
    k_cumsum_c<<<1024, blk, 0, stream>>>(XB, cO, CSUMB);
    k_ln_csum<<<16384, blk, 0, stream>>>(CSUMB, CSB, g_cs, b_cs);
    for (int c = 0; c < NC; ++c) {
        int m0 = c * CH;
        k_gemm_bf16<<<dim3(3, CH / 128, 8), blk, 0, stream>>>(XB, CSB, WTH, b_hid, HIDC, 384, m0);
        k_ln_gates<<<CH, blk, 0, stream>>>(HIDC, FGB, IGB, g_hid, b_hidl, m0);
    }
    k_scan_a<<<512, blk, 0, stream>>>(FGB, IGB, cF, cC);
    k_scan_b<<<16, blk, 0, stream>>>(cF, cC, initcx, cI);
    k_scan_c<<<512, blk, 0, stream>>>(FGB, IGB, cI);
    for (int c = 0; c < NC; ++c) {
        int m0 = c * CH;
        k_gemm_bf16<<<dim3(1, CH / 128, 8), blk, 0, stream>>>(XB, CLB, WTO, b_og, HIDC, 128, m0);
        k_ln_out<<<CH, blk, 0, stream>>>(HIDC, CLB, g_og, b_ogl, (float*)d_out, m0);
    }
}

// Round 8
// 241.951 us; speedup vs baseline: 3.3859x; 1.0643x over previous
//
#include <hip/hip_runtime.h>

#define EPSF 1e-6f

// Shapes: B=4, S=4096, H=8, D=128
// BS = 16384 rows; HD = 1024; ROW3 = 3072; channels = B*H*D = 4096
// All large intermediates bf16 (storage only; math f32). Scan chunking: 64x64 along S.
// GEMM: bf16 MFMA 16x16x32, 128x128 tile, BK=64 double-buffered pipeline (counted vmcnt,
// raw s_barrier), XCD-pinned heads (h = bid&7).

typedef __attribute__((ext_vector_type(8))) short short8v;
typedef __attribute__((ext_vector_type(4))) float float4v;

__device__ __forceinline__ float sigm(float x) { return 1.0f / (1.0f + __expf(-x)); }

__device__ __forceinline__ unsigned short f2bf(float f) {
    unsigned int u = __float_as_uint(f);
    u = (u + 0x7fffu + ((u >> 16) & 1u)) >> 16;   // RNE
    return (unsigned short)u;
}
__device__ __forceinline__ float bf2f(unsigned short s) { return __uint_as_float(((unsigned int)s) << 16); }
__device__ __forceinline__ float bf2f_lo(unsigned int p) { return __uint_as_float(p << 16); }
__device__ __forceinline__ float bf2f_hi(unsigned int p) { return __uint_as_float(p & 0xffff0000u); }
__device__ __forceinline__ unsigned int pack2bf(float a, float b) {
    return (unsigned int)f2bf(a) | ((unsigned int)f2bf(b) << 16);
}

// Block-wide (sum, sumsq) reduction; requires blockDim.x == 256.
__device__ __forceinline__ void block_reduce2(float& a, float& b) {
#pragma unroll
    for (int off = 32; off > 0; off >>= 1) {
        a += __shfl_down(a, off);
        b += __shfl_down(b, off);
    }
    __shared__ float sa[8], sb[8];
    int wid = threadIdx.x >> 6;
    int lane = threadIdx.x & 63;
    if (lane == 0) { sa[wid] = a; sb[wid] = b; }
    __syncthreads();
    a = sa[0] + sa[1] + sa[2] + sa[3];
    b = sb[0] + sb[1] + sb[2] + sb[3];
}

// ---- W transpose+cast: Wt[(h*Nw + o)*256 + k] = bf16(W[(h*256 + k)*Nw + o]) ----
__global__ __launch_bounds__(256) void k_prep_w(const float* __restrict__ W, unsigned short* __restrict__ Wt,
                                                int Nw) {
    int idx = blockIdx.x * 256 + threadIdx.x;
    int k = idx & 255;
    int rest = idx >> 8;
    int o = rest % Nw;
    int h = rest / Nw;
    Wt[idx] = f2bf(W[((size_t)h * 256 + k) * Nw + o]);
}

// ---- cumsum pass A: chunk sums (from bf16-rounded x, consistent with pass C) + emit XB ----
__global__ __launch_bounds__(256) void k_cumsum_a(const float* __restrict__ X, float* __restrict__ cS,
                                                  unsigned short* __restrict__ XB) {
    int t = blockIdx.x * 256 + threadIdx.x;          // 262144
    int d = t & 127, h = (t >> 7) & 7, k = (t >> 10) & 63, b = t >> 16;
    size_t base = (((size_t)(b * 4096 + k * 64)) * 8 + h) * 128 + d;
    float s = 0.f;
    for (int j = 0; j < 64; ++j) {
        unsigned short xb = f2bf(X[base + (size_t)j * 1024]);
        XB[base + (size_t)j * 1024] = xb;
        s += bf2f(xb);
    }
    cS[(size_t)((b * 8 + h) * 128 + d) * 64 + k] = s;
}

__global__ __launch_bounds__(256) void k_cumsum_b(const float* __restrict__ cS, float* __restrict__ cO) {
    int ch = blockIdx.x * 256 + threadIdx.x;          // 4096
    size_t base = (size_t)ch * 64;
    float off = 0.f;
    for (int k = 0; k < 64; ++k) { float v = cS[base + k]; cO[base + k] = off; off += v; }
}

// pass C: exclusive prefix from XB, stored bf16
__global__ __launch_bounds__(256) void k_cumsum_c(const unsigned short* __restrict__ XB,
                                                  const float* __restrict__ cO,
                                                  unsigned short* __restrict__ CSUMB) {
    int t = blockIdx.x * 256 + threadIdx.x;
    int d = t & 127, h = (t >> 7) & 7, k = (t >> 10) & 63, b = t >> 16;
    int ch = (b * 8 + h) * 128 + d;
    float run = cO[(size_t)ch * 64 + k];
    size_t base = (((size_t)(b * 4096 + k * 64)) * 8 + h) * 128 + d;
    for (int j = 0; j < 64; ++j) {
        float x = bf2f(XB[base + (size_t)j * 1024]);
        CSUMB[base + (size_t)j * 1024] = f2bf(run);
        run += x;
    }
}

// ---- LN over (h,d) per (b,s): bf16 in, bf16 out ----
__global__ __launch_bounds__(256) void k_ln_csum(const unsigned short* __restrict__ CSUMB,
                                                 unsigned short* __restrict__ CSB,
                                                 const float* __restrict__ g, const float* __restrict__ bb) {
    int bs = blockIdx.x, t = threadIdx.x;
    uint2 u = ((const uint2*)(CSUMB + (size_t)bs * 1024))[t];
    float4 v;
    v.x = bf2f_lo(u.x); v.y = bf2f_hi(u.x);
    v.z = bf2f_lo(u.y); v.w = bf2f_hi(u.y);
    float s = v.x + v.y + v.z + v.w;
    float ss = v.x * v.x + v.y * v.y + v.z * v.z + v.w * v.w;
    block_reduce2(s, ss);
    float m = s * (1.f / 1024.f);
    float var = ss * (1.f / 1024.f) - m * m;
    float r = rsqrtf(fmaxf(var, 0.f) + EPSF);
    float4 gv = ((const float4*)g)[t];
    float4 bv = ((const float4*)bb)[t];
    uint2 o;
    o.x = pack2bf((v.x - m) * r * gv.x + bv.x, (v.y - m) * r * gv.y + bv.y);
    o.y = pack2bf((v.z - m) * r * gv.z + bv.z, (v.w - m) * r * gv.w + bv.w);
    ((uint2*)(CSB + (size_t)bs * 1024))[t] = o;
}

// ---- bf16 MFMA GEMM, BK=64 double-buffered pipeline ----
// Flat grid: bid -> h = bid&7 (XCD-pinned), rest = bid>>3, bx = rest%nbx, by = rest/nbx.
// K-steps t=0..3: t<2 reads A1 (X), t>=2 reads A2; kofs = (t&1)*64.
// LDS row = 64 bf16 = 8 slots of 16B; slot s of row r holds k-chunk (s ^ (r&7)).
__global__ __launch_bounds__(256) void k_gemm_bf16(const unsigned short* __restrict__ A1,
                                                   const unsigned short* __restrict__ A2,
                                                   const unsigned short* __restrict__ Wt,
                                                   const float* __restrict__ bias,
                                                   unsigned short* __restrict__ OUT, int Nw, int m0,
                                                   int nbx) {
    __shared__ short As[2][8192];   // [buf][128 rows][64 k]
    __shared__ short Bs[2][8192];   // [buf][128 cols][64 k]
    int bid = blockIdx.x;
    int h = bid & 7;
    int rest = bid >> 3;
    int bx = rest % nbx;
    int by = rest / nbx;
    int t0 = threadIdx.x;
    int lane = t0 & 63, wid = t0 >> 6;
    int wr = wid >> 1, wc = wid & 1;
    int l15 = lane & 15, l4 = lane >> 4;
    int lr = lane >> 3, lc = lane & 7;     // stage decomposition: 8 rows x 8 slots
    const int bxc = bx * 128;
    const size_t mbase = (size_t)(m0 + by * 128);

    float4v acc[4][4];
#pragma unroll
    for (int i = 0; i < 4; ++i)
#pragma unroll
        for (int j = 0; j < 4; ++j) acc[i][j] = (float4v)(0.f);

    // stage K-step t into buffer buf: 4 A-issues + 4 B-issues per wave (1KB each)
    auto STAGE = [&](int t, int buf) {
        const unsigned short* src = (t < 2) ? A1 : A2;
        int kofs = (t & 1) * 64;
#pragma unroll
        for (int it = 0; it < 4; ++it) {
            int r0 = wid * 32 + it * 8;
            int r = r0 + lr;
            int c = lc ^ (r & 7);
            size_t g = ((mbase + r) * 8 + h) * 128 + kofs + c * 8;
            __builtin_amdgcn_global_load_lds((const __attribute__((address_space(1))) void*)(src + g),
                                             (__attribute__((address_space(3))) void*)(&As[buf][r0 * 64]),
                                             16, 0, 0);
        }
#pragma unroll
        for (int it = 0; it < 4; ++it) {
            int n0 = wid * 32 + it * 8;
            int cl = n0 + lr;
            int c = lc ^ (cl & 7);
            size_t g = ((size_t)(h * Nw + bxc + cl)) * 256 + t * 64 + c * 8;
            __builtin_amdgcn_global_load_lds((const __attribute__((address_space(1))) void*)(Wt + g),
                                             (__attribute__((address_space(3))) void*)(&Bs[buf][n0 * 64]),
                                             16, 0, 0);
        }
    };

    STAGE(0, 0);
#pragma unroll
    for (int t = 0; t < 4; ++t) {
        int cur = t & 1;
        if (t < 3) STAGE(t + 1, cur ^ 1);
        if (t < 3) asm volatile("s_waitcnt vmcnt(8)" ::: "memory");
        else       asm volatile("s_waitcnt vmcnt(0)" ::: "memory");
        __builtin_amdgcn_s_barrier();
        __builtin_amdgcn_sched_barrier(0);
#pragma unroll
        for (int kk = 0; kk < 2; ++kk) {
            short8v a[4], b[4];
#pragma unroll
            for (int i = 0; i < 4; ++i) {
                int r = wr * 64 + i * 16 + l15;
                int slot = (kk * 4 + l4) ^ (r & 7);
                a[i] = *(const short8v*)(&As[cur][r * 64 + slot * 8]);
            }
#pragma unroll
            for (int j = 0; j < 4; ++j) {
                int c = wc * 64 + j * 16 + l15;
                int slot = (kk * 4 + l4) ^ (c & 7);
                b[j] = *(const short8v*)(&Bs[cur][c * 64 + slot * 8]);
            }
#pragma unroll
            for (int i = 0; i < 4; ++i)
#pragma unroll
                for (int j = 0; j < 4; ++j)
                    acc[i][j] = __builtin_amdgcn_mfma_f32_16x16x32_bf16(a[i], b[j], acc[i][j], 0, 0, 0);
        }
        __builtin_amdgcn_sched_barrier(0);
        __builtin_amdgcn_s_barrier();   // all reads of buf[cur] done before it is restaged
    }
    // epilogue: bias + cvt bf16; C/D: col = lane&15, row = (lane>>4)*4 + q
#pragma unroll
    for (int j = 0; j < 4; ++j) {
        int o = bxc + wc * 64 + j * 16 + l15;
        float bv = bias[h * Nw + o];
#pragma unroll
        for (int i = 0; i < 4; ++i) {
            int mlb = by * 128 + wr * 64 + i * 16 + l4 * 4;
#pragma unroll
            for (int q = 0; q < 4; ++q) {
                OUT[((size_t)(mlb + q) * 8 + h) * Nw + o] = f2bf(acc[i][j][q] + bv);
            }
        }
    }
}

// ---- LN over (h,3,d) + gates; HID bf16 chunk-local; FG/IG bf16 absolute ----
__global__ __launch_bounds__(256) void k_ln_gates(const unsigned short* __restrict__ HID,
                                                  unsigned short* __restrict__ FG,
                                                  unsigned short* __restrict__ IG,
                                                  const float* __restrict__ g, const float* __restrict__ bb,
                                                  int m0) {
    __shared__ float sm[3072];
    int bsl = blockIdx.x, t = threadIdx.x;
    int bs = m0 + bsl;
    const uint4* row = (const uint4*)(HID + (size_t)bsl * 3072);
    float s = 0.f, ss = 0.f;
    for (int idx = t; idx < 384; idx += 256) {
        uint4 u = row[idx];
        float f0 = bf2f_lo(u.x), f1 = bf2f_hi(u.x);
        float f2 = bf2f_lo(u.y), f3 = bf2f_hi(u.y);
        float f4 = bf2f_lo(u.z), f5 = bf2f_hi(u.z);
        float f6 = bf2f_lo(u.w), f7 = bf2f_hi(u.w);
        float* p = sm + idx * 8;
        p[0] = f0; p[1] = f1; p[2] = f2; p[3] = f3; p[4] = f4; p[5] = f5; p[6] = f6; p[7] = f7;
        s += f0 + f1 + f2 + f3 + f4 + f5 + f6 + f7;
        ss += f0 * f0 + f1 * f1 + f2 * f2 + f3 * f3 + f4 * f4 + f5 * f5 + f6 * f6 + f7 * f7;
    }
    block_reduce2(s, ss);
    float m = s * (1.f / 3072.f);
    float var = ss * (1.f / 3072.f) - m * m;
    float r = rsqrtf(fmaxf(var, 0.f) + EPSF);
    int u0 = t * 4;
    int h = u0 >> 7;
    int d0 = u0 & 127;
    float fr[4], ir[4];
#pragma unroll
    for (int q = 0; q < 4; ++q) {
        int d = d0 + q;
        float yi = sm[h * 384 + d];
        float yf = sm[h * 384 + 128 + d];
        float yh = sm[h * 384 + 256 + d];
        float ni = (yi - m) * r * g[(h * 3 + 0) * 128 + d] + bb[(h * 3 + 0) * 128 + d];
        float nf = (yf - m) * r * g[(h * 3 + 1) * 128 + d] + bb[(h * 3 + 1) * 128 + d];
        float nh = (yh - m) * r * g[(h * 3 + 2) * 128 + d] + bb[(h * 3 + 2) * 128 + d];
        fr[q] = sigm(nf);
        ir[q] = sigm(ni) * fmaxf(nh, 0.f);
    }
    uint2 fo, io;
    fo.x = pack2bf(fr[0], fr[1]); fo.y = pack2bf(fr[2], fr[3]);
    io.x = pack2bf(ir[0], ir[1]); io.y = pack2bf(ir[2], ir[3]);
    ((uint2*)(FG + (size_t)bs * 1024))[t] = fo;
    ((uint2*)(IG + (size_t)bs * 1024))[t] = io;
}

// ---- LSTM scan over bf16 gates; 2 channels per thread ----
__global__ __launch_bounds__(256) void k_scan_a(const unsigned short* __restrict__ FG,
                                                const unsigned short* __restrict__ IG,
                                                float* __restrict__ cF, float* __restrict__ cC) {
    int t = blockIdx.x * 256 + threadIdx.x;    // 131072
    int d2 = t & 63, h = (t >> 6) & 7, k = (t >> 9) & 63, b = t >> 15;
    size_t base = (((size_t)(b * 4096 + k * 64)) * 8 + h) * 64 + d2;   // uint index
    const unsigned int* FGu = (const unsigned int*)FG;
    const unsigned int* IGu = (const unsigned int*)IG;
    float F0 = 1.f, C0 = 0.f, F1 = 1.f, C1 = 0.f;
    for (int j = 0; j < 64; ++j) {
        unsigned int fg = FGu[base + (size_t)j * 512];
        unsigned int ig = IGu[base + (size_t)j * 512];
        float f0 = bf2f_lo(fg), f1 = bf2f_hi(fg);
        C0 = fmaf(f0, C0, bf2f_lo(ig)); F0 *= f0;
        C1 = fmaf(f1, C1, bf2f_hi(ig)); F1 *= f1;
    }
    size_t ci0 = ((size_t)((b * 8 + h) * 128 + d2 * 2)) * 64 + k;
    cF[ci0] = F0; cC[ci0] = C0;
    cF[ci0 + 64] = F1; cC[ci0 + 64] = C1;
}

__global__ __launch_bounds__(256) void k_scan_b(const float* __restrict__ cF, const float* __restrict__ cC,
                                                const float* __restrict__ initcx, float* __restrict__ cI) {
    int ch = blockIdx.x * 256 + threadIdx.x;   // 4096
    float c = initcx[ch & 1023];
    size_t base = (size_t)ch * 64;
    for (int k = 0; k < 64; ++k) {
        cI[base + k] = c;
        c = fmaf(cF[base + k], c, cC[base + k]);
    }
}

// final pass: cell (bf16) overwrites IG in place
__global__ __launch_bounds__(256) void k_scan_c(const unsigned short* __restrict__ FG,
                                                unsigned short* __restrict__ IGCLB,
                                                const float* __restrict__ cI) {
    int t = blockIdx.x * 256 + threadIdx.x;    // 131072
    int d2 = t & 63, h = (t >> 6) & 7, k = (t >> 9) & 63, b = t >> 15;
    size_t base = (((size_t)(b * 4096 + k * 64)) * 8 + h) * 64 + d2;
    const unsigned int* FGu = (const unsigned int*)FG;
    unsigned int* IGu = (unsigned int*)IGCLB;
    size_t ci0 = ((size_t)((b * 8 + h) * 128 + d2 * 2)) * 64 + k;
    float c0 = cI[ci0], c1 = cI[ci0 + 64];
    for (int j = 0; j < 64; ++j) {
        unsigned int fg = FGu[base + (size_t)j * 512];
        unsigned int ig = IGu[base + (size_t)j * 512];
        c0 = fmaf(bf2f_lo(fg), c0, bf2f_lo(ig));
        c1 = fmaf(bf2f_hi(fg), c1, bf2f_hi(ig));
        IGu[base + (size_t)j * 512] = pack2bf(c0, c1);
    }
}

// ---- final LN over (h,d) + sigmoid*cell -> out ----
__global__ __launch_bounds__(256) void k_ln_out(const unsigned short* __restrict__ OG,
                                                const unsigned short* __restrict__ CLB,
                                                const float* __restrict__ g, const float* __restrict__ bb,
                                                float* __restrict__ OUT, int m0) {
    int bsl = blockIdx.x, t = threadIdx.x;
    int bs = m0 + bsl;
    uint2 u = ((const uint2*)(OG + (size_t)bsl * 1024))[t];
    float4 v;
    v.x = bf2f_lo(u.x); v.y = bf2f_hi(u.x);
    v.z = bf2f_lo(u.y); v.w = bf2f_hi(u.y);
    float s = v.x + v.y + v.z + v.w;
    float ss = v.x * v.x + v.y * v.y + v.z * v.z + v.w * v.w;
    block_reduce2(s, ss);
    float m = s * (1.f / 1024.f);
    float var = ss * (1.f / 1024.f) - m * m;
    float r = rsqrtf(fmaxf(var, 0.f) + EPSF);
    float4 gv = ((const float4*)g)[t];
    float4 bv = ((const float4*)bb)[t];
    uint2 cu = ((const uint2*)(CLB + (size_t)bs * 1024))[t];
    float4 cv;
    cv.x = bf2f_lo(cu.x); cv.y = bf2f_hi(cu.x);
    cv.z = bf2f_lo(cu.y); cv.w = bf2f_hi(cu.y);
    float4 o;
    o.x = sigm((v.x - m) * r * gv.x + bv.x) * cv.x;
    o.y = sigm((v.y - m) * r * gv.y + bv.y) * cv.y;
    o.z = sigm((v.z - m) * r * gv.z + bv.z) * cv.z;
    o.w = sigm((v.w - m) * r * gv.w + bv.w) * cv.w;
    ((float4*)(OUT + (size_t)bs * 1024))[t] = o;
}

extern "C" void kernel_launch(void* const* d_in, const int* in_sizes, int n_in,
                              void* d_out, int out_size, void* d_ws, size_t ws_size,
                              hipStream_t stream) {
    const float* X      = (const float*)d_in[0];
    const float* W_hid  = (const float*)d_in[1];
    const float* b_hid  = (const float*)d_in[2];
    const float* W_og   = (const float*)d_in[3];
    const float* b_og   = (const float*)d_in[4];
    const float* g_cs   = (const float*)d_in[5];
    const float* b_cs   = (const float*)d_in[6];
    const float* g_hid  = (const float*)d_in[7];
    const float* b_hidl = (const float*)d_in[8];
    const float* g_og   = (const float*)d_in[9];
    const float* b_ogl  = (const float*)d_in[10];
    const float* initcx = (const float*)d_in[11];

    float* ws = (float*)d_ws;
    const size_t O_SC    = 0ull;           // cS,cO,cF,cC,cI: 5 x 262,144 f32
    const size_t O_XB    = 1310720ull;     // XB bf16 (16,777,216 elems = 8,388,608 floats)
    const size_t O_CSUMB = 9699328ull;     // CSUMB bf16; aliased as FGB after ln_csum
    const size_t O_CSB   = 18087936ull;    // CSB bf16
    const size_t O_IGB   = 26476544ull;    // IGB bf16; overwritten in place by cell (CLB)
    const size_t O_WTH   = 34865152ull;    // Wt_hid bf16 (786,432 elems)
    const size_t O_WTO   = 35258368ull;    // Wt_og bf16 (262,144 elems)
    const size_t O_HID   = 35389440ull;    // HIDC bf16 chunk buffer (CH*3072 elems = CH*1536 floats)

    float* cS = ws + O_SC;
    float* cO = cS + 262144;
    float* cF = cO + 262144;
    float* cC = cF + 262144;
    float* cI = cC + 262144;
    unsigned short* XB    = (unsigned short*)(ws + O_XB);
    unsigned short* CSUMB = (unsigned short*)(ws + O_CSUMB);
    unsigned short* FGB   = CSUMB;          // alias: CSUMB dead after ln_csum
    unsigned short* CSB   = (unsigned short*)(ws + O_CSB);
    unsigned short* IGB   = (unsigned short*)(ws + O_IGB);
    unsigned short* CLB   = IGB;            // scan_c overwrites IG with cell in place
    unsigned short* WTH   = (unsigned short*)(ws + O_WTH);
    unsigned short* WTO   = (unsigned short*)(ws + O_WTO);
    unsigned short* HIDC  = (unsigned short*)(ws + O_HID);

    size_t avail = (ws_size / 4 > O_HID) ? ws_size / 4 - O_HID : 0;
    int CH = 1024;
    for (int c = 16384; c >= 1024; c >>= 1) {
        if ((size_t)c * 1536ull <= avail) { CH = c; break; }
    }
    const int NC = 16384 / CH;

    dim3 blk(256);
    k_prep_w<<<3072, blk, 0, stream>>>(W_hid, WTH, 384);
    k_prep_w<<<1024, blk, 0, stream>>>(W_og, WTO, 128);
    k_cumsum_a<<<1024, blk, 0, stream>>>(X, cS, XB);
    k_cumsum_b<<<16, blk, 0, stream>>>(cS, cO);
    k_cumsum_c<<<1024, blk, 0, stream>>>(XB, cO, CSUMB);
    k_ln_csum<<<16384, blk, 0, stream>>>(CSUMB, CSB, g_cs, b_cs);
    for (int c = 0; c < NC; ++c) {
        int m0 = c * CH;
        k_gemm_bf16<<<8 * 3 * (CH / 128), blk, 0, stream>>>(XB, CSB, WTH, b_hid, HIDC, 384, m0, 3);
        k_ln_gates<<<CH, blk, 0, stream>>>(HIDC, FGB, IGB, g_hid, b_hidl, m0);
    }
    k_scan_a<<<512, blk, 0, stream>>>(FGB, IGB, cF, cC);
    k_scan_b<<<16, blk, 0, stream>>>(cF, cC, initcx, cI);
    k_scan_c<<<512, blk, 0, stream>>>(FGB, IGB, cI);
    for (int c = 0; c < NC; ++c) {
        int m0 = c * CH;
        k_gemm_bf16<<<8 * 1 * (CH / 128), blk, 0, stream>>>(XB, CLB, WTO, b_og, HIDC, 128, m0, 1);
        k_ln_out<<<CH, blk, 0, stream>>>(HIDC, CLB, g_og, b_ogl, (float*)d_out, m0);
    }
}